// Round 8
// baseline (233.816 us; speedup 1.0000x reference)
//
#include <hip/hip_runtime.h>
#include <hip/hip_bf16.h>

// out[b,s,c] = x[b,s,:] @ W, W[r][c] = kernel[(r%512)*4096 + c]
// xr[m][r'] = sum_{i<8} x[m][r'+512i]  (M=8192, K'=512)
// INT8 GEMM: xq = clamp(round(xr*8),-127,127); btq = kernel^T i8 (exact).
// out = i32 acc * 0.125f.
// Round 8: R5 structure, but gemm uses 2 LDS buffers (64KB) -> 2 blocks/CU
// so the per-K-step vmcnt+barrier drain is hidden by the co-resident block.

#define M_TOT   8192
#define N_TOT   4096
#define K_RED   512
#define K_FULL  4096
#define NSTEP   8           // K_RED / 64

typedef __attribute__((ext_vector_type(4))) int   i32x4;
typedef __attribute__((ext_vector_type(4))) float f32x4;

// ---------------------------------------------------------------------------
// Prep: blocks [0,4096): xq[m][r'] = i8(clamp(round(8*sum_{i<8} x[m][r'+512i])))
//       blocks [4096,4608): btq[c][r'] = i8(kernel[r'*4096 + c])  (transpose)
// (validated R5)
// ---------------------------------------------------------------------------
__global__ __launch_bounds__(256) void prep(const float* __restrict__ x,
                                            const int* __restrict__ kin,
                                            char* __restrict__ xq,
                                            char* __restrict__ btq) {
    __shared__ char tile[64][68];
    if (blockIdx.x < 4096) {
        const int row = blockIdx.x * 2 + (threadIdx.x >> 7);
        const int t2  = threadIdx.x & 127;
        const float* xp = x + (size_t)row * K_FULL + t2 * 4;
        float a0 = 0.f, a1 = 0.f, a2 = 0.f, a3 = 0.f;
#pragma unroll
        for (int i = 0; i < 8; ++i) {
            float4 v = *reinterpret_cast<const float4*>(xp + (size_t)i * K_RED);
            a0 += v.x; a1 += v.y; a2 += v.z; a3 += v.w;
        }
        int q0 = (int)rintf(a0 * 8.f), q1 = (int)rintf(a1 * 8.f);
        int q2 = (int)rintf(a2 * 8.f), q3 = (int)rintf(a3 * 8.f);
        q0 = min(127, max(-127, q0)); q1 = min(127, max(-127, q1));
        q2 = min(127, max(-127, q2)); q3 = min(127, max(-127, q3));
        int packed = (q0 & 0xFF) | ((q1 & 0xFF) << 8) | ((q2 & 0xFF) << 16)
                   | ((q3 & 0xFF) << 24);
        *reinterpret_cast<int*>(xq + (size_t)row * K_RED + t2 * 4) = packed;
    } else {
        const int b  = blockIdx.x - 4096;        // 0..511
        const int c0 = (b & 63) * 64;
        const int r0 = (b >> 6) * 64;
        const int tx = threadIdx.x & 63;
        const int ty = threadIdx.x >> 6;         // 0..3
#pragma unroll
        for (int rr = 0; rr < 64; rr += 4) {
            int r = r0 + rr + ty;
            tile[rr + ty][tx] = (char)kin[(size_t)r * N_TOT + c0 + tx];
        }
        __syncthreads();
        const int q  = tx & 15;                  // r'-quad (r' = q*4+j)
        const int ch = tx >> 4;                  // 0..3
#pragma unroll
        for (int i = 0; i < 4; ++i) {
            const int cl = i * 16 + ty * 4 + ch; // column offset 0..63
            int p = (tile[q * 4 + 0][cl] & 0xFF)
                  | ((tile[q * 4 + 1][cl] & 0xFF) << 8)
                  | ((tile[q * 4 + 2][cl] & 0xFF) << 16)
                  | ((tile[q * 4 + 3][cl] & 0xFF) << 24);
            *reinterpret_cast<int*>(btq + (size_t)(c0 + cl) * K_RED + r0 + q * 4) = p;
        }
    }
}

// ---------------------------------------------------------------------------
// GEMM: C[8192][4096] f32 = (xq i8 @ btq^T i8) * 0.125
// 256x256 tile, 512 thr = 8 waves (2Mx4N), BK=64, 2 LDS buffers x 32KB = 64KB
// -> 2 blocks/CU. T3-minimal schedule: stage(t+1) BEFORE compute(t); one
// vmcnt(0)+barrier per step.
// ---------------------------------------------------------------------------
__global__ __launch_bounds__(512, 4) void gemm_i8(const char* __restrict__ A,
                                                  const char* __restrict__ Bt,
                                                  float* __restrict__ C) {
    __shared__ char smem[2 * 32768];

    const int tid  = threadIdx.x;
    const int lane = tid & 63;
    const int w    = tid >> 6;        // 0..7
    const int wr   = w >> 2;          // 0..1  (M half)
    const int wc   = w & 3;           // 0..3  (N quarter)
    const int l15  = lane & 15;
    const int lhi  = lane >> 4;       // 0..3  (k-group)

    // XCD-aware bijective swizzle (512 blocks, 512 % 8 == 0)
    const int wg  = blockIdx.x;
    const int swz = (wg & 7) * 64 + (wg >> 3);
    const int m0  = (swz >> 4) * 256;    // 32 m-blocks
    const int n0  = (swz & 15) * 256;    // 16 n-blocks

    auto stage = [&](int buf, int t) {
        const int sb = buf * 32768;
#pragma unroll
        for (int it = 0; it < 2; ++it) {
            const int o   = (it * 512 + tid) * 16;   // byte in 16KB tile
            const int g   = o >> 12;                 // k-group 0..3
            const int row = (o & 4095) >> 4;         // 0..255
            const char* ga = A  + (size_t)(m0 + row) * K_RED + t * 64 + g * 16;
            const char* gb = Bt + (size_t)(n0 + row) * K_RED + t * 64 + g * 16;
            __builtin_amdgcn_global_load_lds(
                (__attribute__((address_space(1))) void*)ga,
                (__attribute__((address_space(3))) void*)(smem + sb + o), 16, 0, 0);
            __builtin_amdgcn_global_load_lds(
                (__attribute__((address_space(1))) void*)gb,
                (__attribute__((address_space(3))) void*)(smem + sb + 16384 + o), 16, 0, 0);
        }
    };

    int offA[8], offB[4];
#pragma unroll
    for (int mi = 0; mi < 8; ++mi)
        offA[mi] = (lhi << 12) + ((wr * 128 + mi * 16 + l15) << 4);
#pragma unroll
    for (int ni = 0; ni < 4; ++ni)
        offB[ni] = 16384 + (lhi << 12) + ((wc * 64 + ni * 16 + l15) << 4);

    i32x4 acc[8][4] = {};

    // Prologue: buf0 for step 0; wait + barrier.
    stage(0, 0);
    asm volatile("s_waitcnt vmcnt(0)" ::: "memory");
    __builtin_amdgcn_s_barrier();
    asm volatile("" ::: "memory");

    for (int t = 0; t < NSTEP; ++t) {
        const int cur = t & 1;
        if (t < NSTEP - 1)
            stage(cur ^ 1, t + 1);       // issue next-tile loads FIRST
        asm volatile("" ::: "memory");
        const int sb = cur * 32768;
        i32x4 af[8], bfr[4];
#pragma unroll
        for (int mi = 0; mi < 8; ++mi)
            af[mi] = *reinterpret_cast<const i32x4*>(smem + sb + offA[mi]);
#pragma unroll
        for (int ni = 0; ni < 4; ++ni)
            bfr[ni] = *reinterpret_cast<const i32x4*>(smem + sb + offB[ni]);
        __builtin_amdgcn_s_setprio(1);
#pragma unroll
        for (int mi = 0; mi < 8; ++mi)
#pragma unroll
            for (int ni = 0; ni < 4; ++ni)
                acc[mi][ni] = __builtin_amdgcn_mfma_i32_16x16x64_i8(
                    af[mi], bfr[ni], acc[mi][ni], 0, 0, 0);
        __builtin_amdgcn_s_setprio(0);
        asm volatile("" ::: "memory");
        if (t < NSTEP - 1) {
            asm volatile("s_waitcnt vmcnt(0)" ::: "memory");  // next tile landed
            __builtin_amdgcn_s_barrier();
            asm volatile("" ::: "memory");
        }
    }

    // ---- Epilogue via per-wave LDS transpose -> dwordx4 stores ----
    // buf0 regions: last compute step (t=7) reads buf1 only; buf0 is dead
    // since the t==6 end barrier -> safe, no extra barrier (validated R5).
    float* ep = reinterpret_cast<float*>(smem + w * 4096);   // [16][64] f32
#pragma unroll
    for (int mi = 0; mi < 8; ++mi) {
#pragma unroll
        for (int ni = 0; ni < 4; ++ni)
#pragma unroll
            for (int r = 0; r < 4; ++r)
                ep[(lhi * 4 + r) * 64 + ni * 16 + l15] =
                    (float)acc[mi][ni][r] * 0.125f;
        __builtin_amdgcn_s_waitcnt(0);  // lgkmcnt(0): writes visible
#pragma unroll
        for (int j = 0; j < 4; ++j) {
            const int row = j * 4 + lhi;        // 0..15
            const int c4  = l15 * 4;            // 0..60
            f32x4 v = *reinterpret_cast<const f32x4*>(&ep[row * 64 + c4]);
            const size_t gr = (size_t)(m0 + wr * 128 + mi * 16 + row);
            *reinterpret_cast<f32x4*>(&C[gr * N_TOT + n0 + wc * 64 + c4]) = v;
        }
        __builtin_amdgcn_s_waitcnt(0);  // reads done before next mi overwrites
    }
}

// ---------------------------------------------------------------------------
extern "C" void kernel_launch(void* const* d_in, const int* in_sizes, int n_in,
                              void* d_out, int out_size, void* d_ws, size_t ws_size,
                              hipStream_t stream) {
    const float* x   = (const float*)d_in[0];       // [2,4096,4096] f32
    const int*   kin = (const int*)d_in[1];         // [2097152] int32 in {-1,0,1}
    float*       out = (float*)d_out;               // [2,4096,4096] f32

    char* xq  = (char*)d_ws;                                    // 4 MB
    char* btq = (char*)d_ws + (size_t)M_TOT * K_RED;            // 2 MB

    prep<<<dim3(4096 + 512), 256, 0, stream>>>(x, kin, xq, btq);
    gemm_i8<<<dim3((M_TOT / 256) * (N_TOT / 256)), 512, 0, stream>>>(xq, btq, out);
}

// Round 9
// 61.057 us; speedup vs baseline: 3.8294x; 3.8294x over previous
//
#include <hip/hip_runtime.h>
#include <hip/hip_bf16.h>

// out[b,s,c] = x[b,s,:] @ W, W[r][c] = kernel[(r%512)*4096 + c]
// xr[m][r'] = sum_{i<8} x[m][r'+512i]  (M=8192, K'=512)
// INT8: xq = clamp(round(xr*8),-127,127); btq = kernel^T i8; out = acc*0.125f.
// Round 9: A-resident GEMM. Block = 128 rows x full K in LDS (64KB, swizzled)
// + per-wave A-frags in regs; loop over 32-col N-steps with double-buffered
// B-tile (16KB each); C stores STREAMED every step; vmcnt(8) never waits on
// stores. LDS 96KB, launch_bounds(512,2) -> no spill (R8 lesson).

#define M_TOT   8192
#define N_TOT   4096
#define K_RED   512
#define K_FULL  4096
#define NSTEPS  32          // 1024-col stripe / 32

typedef __attribute__((ext_vector_type(4))) int   i32x4;
typedef __attribute__((ext_vector_type(4))) float f32x4;

// ---------------------------------------------------------------------------
// Prep (validated R5): blocks [0,4096): xq = i8 of 8-way reduced x (scale 8);
// blocks [4096,4608): btq[c][r'] = i8(kernel[r'*4096 + c]).
// ---------------------------------------------------------------------------
__global__ __launch_bounds__(256) void prep(const float* __restrict__ x,
                                            const int* __restrict__ kin,
                                            char* __restrict__ xq,
                                            char* __restrict__ btq) {
    __shared__ char tile[64][68];
    if (blockIdx.x < 4096) {
        const int row = blockIdx.x * 2 + (threadIdx.x >> 7);
        const int t2  = threadIdx.x & 127;
        const float* xp = x + (size_t)row * K_FULL + t2 * 4;
        float a0 = 0.f, a1 = 0.f, a2 = 0.f, a3 = 0.f;
#pragma unroll
        for (int i = 0; i < 8; ++i) {
            float4 v = *reinterpret_cast<const float4*>(xp + (size_t)i * K_RED);
            a0 += v.x; a1 += v.y; a2 += v.z; a3 += v.w;
        }
        int q0 = (int)rintf(a0 * 8.f), q1 = (int)rintf(a1 * 8.f);
        int q2 = (int)rintf(a2 * 8.f), q3 = (int)rintf(a3 * 8.f);
        q0 = min(127, max(-127, q0)); q1 = min(127, max(-127, q1));
        q2 = min(127, max(-127, q2)); q3 = min(127, max(-127, q3));
        int packed = (q0 & 0xFF) | ((q1 & 0xFF) << 8) | ((q2 & 0xFF) << 16)
                   | ((q3 & 0xFF) << 24);
        *reinterpret_cast<int*>(xq + (size_t)row * K_RED + t2 * 4) = packed;
    } else {
        const int b  = blockIdx.x - 4096;        // 0..511
        const int c0 = (b & 63) * 64;
        const int r0 = (b >> 6) * 64;
        const int tx = threadIdx.x & 63;
        const int ty = threadIdx.x >> 6;         // 0..3
#pragma unroll
        for (int rr = 0; rr < 64; rr += 4) {
            int r = r0 + rr + ty;
            tile[rr + ty][tx] = (char)kin[(size_t)r * N_TOT + c0 + tx];
        }
        __syncthreads();
        const int q  = tx & 15;                  // r'-quad (r' = q*4+j)
        const int ch = tx >> 4;                  // 0..3
#pragma unroll
        for (int i = 0; i < 4; ++i) {
            const int cl = i * 16 + ty * 4 + ch; // column offset 0..63
            int p = (tile[q * 4 + 0][cl] & 0xFF)
                  | ((tile[q * 4 + 1][cl] & 0xFF) << 8)
                  | ((tile[q * 4 + 2][cl] & 0xFF) << 16)
                  | ((tile[q * 4 + 3][cl] & 0xFF) << 24);
            *reinterpret_cast<int*>(btq + (size_t)(c0 + cl) * K_RED + r0 + q * 4) = p;
        }
    }
}

// ---------------------------------------------------------------------------
// A-resident streamed GEMM.
// Grid 256 = 64 M-tiles(128 rows) x 4 N-stripes(1024 cols); 512 thr = 8 waves,
// wave w owns rows w*16..w*16+15 for the whole stripe.
// LDS: A[128][512B swizzled] = 64KB  |  B dbuf 2 x [32][512B swizzled] = 32KB.
// Swizzle (both sides): kbyte ^= (row&7)<<4  within each 512B row.
// ---------------------------------------------------------------------------
__global__ __launch_bounds__(512, 2) void gemm_as(const char* __restrict__ A,
                                                  const char* __restrict__ Bt,
                                                  float* __restrict__ C) {
    __shared__ char smem[98304];     // [0,64K): A   [64K,96K): B dbuf

    const int tid  = threadIdx.x;
    const int lane = tid & 63;
    const int w    = tid >> 6;       // 0..7 -> m-slice
    const int l15  = lane & 15;
    const int lhi  = lane >> 4;      // 0..3 (k-group)

    // XCD mapping: xcd = b&7 handles stripe xcd>>1; 32 blocks/XCD share the
    // 512KB B-stripe (L2-resident). Bijective over 256 blocks.
    const int b   = blockIdx.x;
    const int n0  = ((b & 7) >> 1) * 1024;
    const int m0  = ((b >> 3) + 32 * (b & 1)) * 128;

    // ---- Stage A panel (128 rows x 512 K), swizzled source -> linear LDS ----
#pragma unroll
    for (int p = 0; p < 8; ++p) {
        const int o   = (p * 512 + tid) * 16;
        const int row = o >> 9;
        const int kb  = o & 511;
        const char* ga = A + (size_t)(m0 + row) * K_RED + (kb ^ ((row & 7) << 4));
        __builtin_amdgcn_global_load_lds(
            (__attribute__((address_space(1))) void*)ga,
            (__attribute__((address_space(3))) void*)(smem + o), 16, 0, 0);
    }

    auto stageB = [&](int buf, int s) {
        const int sb = 65536 + buf * 16384;
#pragma unroll
        for (int it = 0; it < 2; ++it) {
            const int o   = (it * 512 + tid) * 16;
            const int col = o >> 9;              // 0..31
            const int kb  = o & 511;
            const char* gb = Bt + (size_t)(n0 + s * 32 + col) * K_RED
                               + (kb ^ ((col & 7) << 4));
            __builtin_amdgcn_global_load_lds(
                (__attribute__((address_space(1))) void*)gb,
                (__attribute__((address_space(3))) void*)(smem + sb + o), 16, 0, 0);
        }
    };

    stageB(0, 0);
    asm volatile("s_waitcnt vmcnt(0)" ::: "memory");
    __builtin_amdgcn_s_barrier();
    asm volatile("" ::: "memory");

    // ---- Per-wave A fragments (held in registers for the whole kernel) ----
    const int swz = (l15 & 7) << 4;
    i32x4 af[8];
    {
        const int abase = (w * 16 + l15) * 512;
#pragma unroll
        for (int ks = 0; ks < 8; ++ks)
            af[ks] = *reinterpret_cast<const i32x4*>(
                smem + abase + ((ks * 64 + lhi * 16) ^ swz));
    }

    // ---- N-step loop: stage next-B, compute, stream stores ----
    for (int s = 0; s < NSTEPS; ++s) {
        const int buf = s & 1;
        if (s < NSTEPS - 1)
            stageB(buf ^ 1, s + 1);
        asm volatile("" ::: "memory");
        const int sb = 65536 + buf * 16384;
        i32x4 acc0 = {}, acc1 = {};
        {
            const int b0 = sb + l15 * 512;
            const int b1 = sb + (16 + l15) * 512;
            i32x4 bf0[8], bf1[8];
#pragma unroll
            for (int ks = 0; ks < 8; ++ks) {
                const int ko = (ks * 64 + lhi * 16) ^ swz;
                bf0[ks] = *reinterpret_cast<const i32x4*>(smem + b0 + ko);
                bf1[ks] = *reinterpret_cast<const i32x4*>(smem + b1 + ko);
            }
            __builtin_amdgcn_s_setprio(1);
#pragma unroll
            for (int ks = 0; ks < 8; ++ks) {
                acc0 = __builtin_amdgcn_mfma_i32_16x16x64_i8(af[ks], bf0[ks], acc0, 0, 0, 0);
                acc1 = __builtin_amdgcn_mfma_i32_16x16x64_i8(af[ks], bf1[ks], acc1, 0, 0, 0);
            }
            __builtin_amdgcn_s_setprio(0);
        }
        // streamed stores: C/D frag col=l15, row=lhi*4+r
        const int colb = n0 + s * 32;
        const size_t rb = (size_t)(m0 + w * 16 + lhi * 4);
#pragma unroll
        for (int r = 0; r < 4; ++r) {
            C[(rb + r) * N_TOT + colb + l15]      = (float)acc0[r] * 0.125f;
            C[(rb + r) * N_TOT + colb + 16 + l15] = (float)acc1[r] * 0.125f;
        }
        asm volatile("" ::: "memory");
        if (s < NSTEPS - 1) {
            // 2 B-loads (oldest) + 8 stores (newest) outstanding:
            // vmcnt(8) retires the loads, never waits on the stores.
            asm volatile("s_waitcnt vmcnt(8)" ::: "memory");
            __builtin_amdgcn_s_barrier();
            asm volatile("" ::: "memory");
        }
    }
}

// ---------------------------------------------------------------------------
extern "C" void kernel_launch(void* const* d_in, const int* in_sizes, int n_in,
                              void* d_out, int out_size, void* d_ws, size_t ws_size,
                              hipStream_t stream) {
    const float* x   = (const float*)d_in[0];       // [2,4096,4096] f32
    const int*   kin = (const int*)d_in[1];         // [2097152] int32 in {-1,0,1}
    float*       out = (float*)d_out;               // [2,4096,4096] f32

    char* xq  = (char*)d_ws;                                    // 4 MB
    char* btq = (char*)d_ws + (size_t)M_TOT * K_RED;            // 2 MB

    prep<<<dim3(4096 + 512), 256, 0, stream>>>(x, kin, xq, btq);
    gemm_as<<<dim3(256), 512, 0, stream>>>(xq, btq, out);
}

// Round 10
// 60.761 us; speedup vs baseline: 3.8481x; 1.0049x over previous
//
#include <hip/hip_runtime.h>
#include <hip/hip_bf16.h>

// out[b,s,c] = x[b,s,:] @ W, W[r][c] = kernel[(r%512)*4096 + c]
// xr[m][r'] = sum_{i<8} x[m][r'+512i]  (M=8192, K'=512)
// INT8: xq = clamp(round(xr*8),-127,127); btq = kernel^T i8; out = acc*0.125f.
// Round 10: A-frags global->reg (no A-LDS); LDS = 32KB B dbuf only -> 2
// blocks/CU at grid 512. Waves 4Mx2N (32 rows x 16 cols) halves B ds_reads.
// Streamed stores + vmcnt(8) per step (never waits on stores).

#define M_TOT   8192
#define N_TOT   4096
#define K_RED   512
#define K_FULL  4096
#define NSTEPS  16          // 512-col stripe / 32

typedef __attribute__((ext_vector_type(4))) int   i32x4;
typedef __attribute__((ext_vector_type(4))) float f32x4;

// ---------------------------------------------------------------------------
// Prep (validated R5): blocks [0,4096): xq = i8 of 8-way reduced x (scale 8);
// blocks [4096,4608): btq[c][r'] = i8(kernel[r'*4096 + c]).
// ---------------------------------------------------------------------------
__global__ __launch_bounds__(256) void prep(const float* __restrict__ x,
                                            const int* __restrict__ kin,
                                            char* __restrict__ xq,
                                            char* __restrict__ btq) {
    __shared__ char tile[64][68];
    if (blockIdx.x < 4096) {
        const int row = blockIdx.x * 2 + (threadIdx.x >> 7);
        const int t2  = threadIdx.x & 127;
        const float* xp = x + (size_t)row * K_FULL + t2 * 4;
        float a0 = 0.f, a1 = 0.f, a2 = 0.f, a3 = 0.f;
#pragma unroll
        for (int i = 0; i < 8; ++i) {
            float4 v = *reinterpret_cast<const float4*>(xp + (size_t)i * K_RED);
            a0 += v.x; a1 += v.y; a2 += v.z; a3 += v.w;
        }
        int q0 = (int)rintf(a0 * 8.f), q1 = (int)rintf(a1 * 8.f);
        int q2 = (int)rintf(a2 * 8.f), q3 = (int)rintf(a3 * 8.f);
        q0 = min(127, max(-127, q0)); q1 = min(127, max(-127, q1));
        q2 = min(127, max(-127, q2)); q3 = min(127, max(-127, q3));
        int packed = (q0 & 0xFF) | ((q1 & 0xFF) << 8) | ((q2 & 0xFF) << 16)
                   | ((q3 & 0xFF) << 24);
        *reinterpret_cast<int*>(xq + (size_t)row * K_RED + t2 * 4) = packed;
    } else {
        const int b  = blockIdx.x - 4096;        // 0..511
        const int c0 = (b & 63) * 64;
        const int r0 = (b >> 6) * 64;
        const int tx = threadIdx.x & 63;
        const int ty = threadIdx.x >> 6;         // 0..3
#pragma unroll
        for (int rr = 0; rr < 64; rr += 4) {
            int r = r0 + rr + ty;
            tile[rr + ty][tx] = (char)kin[(size_t)r * N_TOT + c0 + tx];
        }
        __syncthreads();
        const int q  = tx & 15;                  // r'-quad (r' = q*4+j)
        const int ch = tx >> 4;                  // 0..3
#pragma unroll
        for (int i = 0; i < 4; ++i) {
            const int cl = i * 16 + ty * 4 + ch; // column offset 0..63
            int p = (tile[q * 4 + 0][cl] & 0xFF)
                  | ((tile[q * 4 + 1][cl] & 0xFF) << 8)
                  | ((tile[q * 4 + 2][cl] & 0xFF) << 16)
                  | ((tile[q * 4 + 3][cl] & 0xFF) << 24);
            *reinterpret_cast<int*>(btq + (size_t)(c0 + cl) * K_RED + r0 + q * 4) = p;
        }
    }
}

// ---------------------------------------------------------------------------
// A-resident streamed GEMM v2.
// Grid 512 = 64 M-tiles(128 rows) x 8 N-stripes(512 cols). 512 thr = 8 waves:
// wm = w&3 (rows wm*32..+31), wn = w>>2 (col-half). LDS = 2 x 16KB B dbuf.
// B swizzle both sides: kb ^= (col&7)<<4 within each 512B col-row.
// ---------------------------------------------------------------------------
__global__ __launch_bounds__(512, 4) void gemm_as2(const char* __restrict__ A,
                                                   const char* __restrict__ Bt,
                                                   float* __restrict__ C) {
    __shared__ char smem[32768];     // 2 x 16KB B double-buffer

    const int tid  = threadIdx.x;
    const int lane = tid & 63;
    const int w    = tid >> 6;       // 0..7
    const int wm   = w & 3;          // m-slice (32 rows)
    const int wn   = w >> 2;         // col-half (16 of 32)
    const int l15  = lane & 15;
    const int lhi  = lane >> 4;      // 0..3 (k-group)

    const int b   = blockIdx.x;
    const int n0  = (b & 7) * 512;   // XCD b&7 owns this 256KB B-stripe (L2)
    const int m0  = (b >> 3) * 128;

    auto stageB = [&](int buf, int s) {
        const int sb = buf * 16384;
#pragma unroll
        for (int it = 0; it < 2; ++it) {
            const int o   = (it * 512 + tid) * 16;
            const int col = o >> 9;              // 0..31
            const int kb  = o & 511;
            const char* gb = Bt + (size_t)(n0 + s * 32 + col) * K_RED
                               + (kb ^ ((col & 7) << 4));
            __builtin_amdgcn_global_load_lds(
                (__attribute__((address_space(1))) void*)gb,
                (__attribute__((address_space(3))) void*)(smem + sb + o), 16, 0, 0);
        }
    };

    // Prologue: first B tile staging overlaps direct A-frag loads.
    stageB(0, 0);
    i32x4 af[2][8];
#pragma unroll
    for (int h = 0; h < 2; ++h) {
        const char* ap = A + (size_t)(m0 + wm * 32 + h * 16 + l15) * K_RED
                           + lhi * 16;
#pragma unroll
        for (int ks = 0; ks < 8; ++ks)
            af[h][ks] = *reinterpret_cast<const i32x4*>(ap + ks * 64);
    }
    asm volatile("s_waitcnt vmcnt(0)" ::: "memory");
    __builtin_amdgcn_s_barrier();
    asm volatile("" ::: "memory");

    const int swz = (l15 & 7) << 4;
    const int cin = wn * 16 + l15;           // within-tile col 0..31

    for (int s = 0; s < NSTEPS; ++s) {
        const int buf = s & 1;
        if (s < NSTEPS - 1)
            stageB(buf ^ 1, s + 1);
        asm volatile("" ::: "memory");
        const int base = buf * 16384 + cin * 512;
        i32x4 acc0 = {}, acc1 = {};
#pragma unroll
        for (int g = 0; g < 2; ++g) {        // bf in 2 batches (VGPR pressure)
            i32x4 bf[4];
#pragma unroll
            for (int k4 = 0; k4 < 4; ++k4) {
                const int ks = g * 4 + k4;
                bf[k4] = *reinterpret_cast<const i32x4*>(
                    smem + base + ((ks * 64 + lhi * 16) ^ swz));
            }
            __builtin_amdgcn_s_setprio(1);
#pragma unroll
            for (int k4 = 0; k4 < 4; ++k4) {
                const int ks = g * 4 + k4;
                acc0 = __builtin_amdgcn_mfma_i32_16x16x64_i8(af[0][ks], bf[k4], acc0, 0, 0, 0);
                acc1 = __builtin_amdgcn_mfma_i32_16x16x64_i8(af[1][ks], bf[k4], acc1, 0, 0, 0);
            }
            __builtin_amdgcn_s_setprio(0);
        }
        // streamed stores: C/D frag col=l15(+wn*16), row=lhi*4+r (+h*16)
        const int    colb = n0 + s * 32 + cin;
        const size_t rb   = (size_t)(m0 + wm * 32 + lhi * 4);
#pragma unroll
        for (int r = 0; r < 4; ++r) {
            C[(rb + r) * N_TOT + colb]      = (float)acc0[r] * 0.125f;
            C[(rb + 16 + r) * N_TOT + colb] = (float)acc1[r] * 0.125f;
        }
        asm volatile("" ::: "memory");
        if (s < NSTEPS - 1) {
            // outstanding: [older stores][2 B-loads][8 stores]; vmcnt(8)
            // retires the loads, never waits on this step's stores.
            asm volatile("s_waitcnt vmcnt(8)" ::: "memory");
            __builtin_amdgcn_s_barrier();
            asm volatile("" ::: "memory");
        }
    }
}

// ---------------------------------------------------------------------------
extern "C" void kernel_launch(void* const* d_in, const int* in_sizes, int n_in,
                              void* d_out, int out_size, void* d_ws, size_t ws_size,
                              hipStream_t stream) {
    const float* x   = (const float*)d_in[0];       // [2,4096,4096] f32
    const int*   kin = (const int*)d_in[1];         // [2097152] int32 in {-1,0,1}
    float*       out = (float*)d_out;               // [2,4096,4096] f32

    char* xq  = (char*)d_ws;                                    // 4 MB
    char* btq = (char*)d_ws + (size_t)M_TOT * K_RED;            // 2 MB

    prep<<<dim3(4096 + 512), 256, 0, stream>>>(x, kin, xq, btq);
    gemm_as2<<<dim3(512), 512, 0, stream>>>(xq, btq, out);
}

// Round 11
// 56.165 us; speedup vs baseline: 4.1630x; 1.0818x over previous
//
#include <hip/hip_runtime.h>
#include <hip/hip_bf16.h>

// out[b,s,c] = x[b,s,:] @ W, W[r][c] = kernel[(r%512)*4096 + c]
// xr[m][r'] = sum_{i<8} x[m][r'+512i]  (M=8192, K'=512)
// INT8: xq = clamp(round(xr*8),-127,127); btq = kernel^T i8; out = acc*0.125f.
// Round 11: SWAPPED-OPERAND MFMA (mfma(bf, af)) -> D fragment transposed:
// lane holds 4 CONSECUTIVE n-columns -> global_store_dwordx4 (16B/lane,
// 1KB/instr, fill-kernel store pattern). Waves = 8 m-slices x full 32 cols
// so one wave covers each 128B line. vmcnt(2) per step.

#define M_TOT   8192
#define N_TOT   4096
#define K_RED   512
#define K_FULL  4096
#define NSTEPS  16          // 512-col stripe / 32

typedef __attribute__((ext_vector_type(4))) int   i32x4;
typedef __attribute__((ext_vector_type(4))) float f32x4;

// ---------------------------------------------------------------------------
// Prep (validated R5): blocks [0,4096): xq = i8 of 8-way reduced x (scale 8);
// blocks [4096,4608): btq[c][r'] = i8(kernel[r'*4096 + c]).
// ---------------------------------------------------------------------------
__global__ __launch_bounds__(256) void prep(const float* __restrict__ x,
                                            const int* __restrict__ kin,
                                            char* __restrict__ xq,
                                            char* __restrict__ btq) {
    __shared__ char tile[64][68];
    if (blockIdx.x < 4096) {
        const int row = blockIdx.x * 2 + (threadIdx.x >> 7);
        const int t2  = threadIdx.x & 127;
        const float* xp = x + (size_t)row * K_FULL + t2 * 4;
        float a0 = 0.f, a1 = 0.f, a2 = 0.f, a3 = 0.f;
#pragma unroll
        for (int i = 0; i < 8; ++i) {
            float4 v = *reinterpret_cast<const float4*>(xp + (size_t)i * K_RED);
            a0 += v.x; a1 += v.y; a2 += v.z; a3 += v.w;
        }
        int q0 = (int)rintf(a0 * 8.f), q1 = (int)rintf(a1 * 8.f);
        int q2 = (int)rintf(a2 * 8.f), q3 = (int)rintf(a3 * 8.f);
        q0 = min(127, max(-127, q0)); q1 = min(127, max(-127, q1));
        q2 = min(127, max(-127, q2)); q3 = min(127, max(-127, q3));
        int packed = (q0 & 0xFF) | ((q1 & 0xFF) << 8) | ((q2 & 0xFF) << 16)
                   | ((q3 & 0xFF) << 24);
        *reinterpret_cast<int*>(xq + (size_t)row * K_RED + t2 * 4) = packed;
    } else {
        const int b  = blockIdx.x - 4096;        // 0..511
        const int c0 = (b & 63) * 64;
        const int r0 = (b >> 6) * 64;
        const int tx = threadIdx.x & 63;
        const int ty = threadIdx.x >> 6;         // 0..3
#pragma unroll
        for (int rr = 0; rr < 64; rr += 4) {
            int r = r0 + rr + ty;
            tile[rr + ty][tx] = (char)kin[(size_t)r * N_TOT + c0 + tx];
        }
        __syncthreads();
        const int q  = tx & 15;                  // r'-quad (r' = q*4+j)
        const int ch = tx >> 4;                  // 0..3
#pragma unroll
        for (int i = 0; i < 4; ++i) {
            const int cl = i * 16 + ty * 4 + ch; // column offset 0..63
            int p = (tile[q * 4 + 0][cl] & 0xFF)
                  | ((tile[q * 4 + 1][cl] & 0xFF) << 8)
                  | ((tile[q * 4 + 2][cl] & 0xFF) << 16)
                  | ((tile[q * 4 + 3][cl] & 0xFF) << 24);
            *reinterpret_cast<int*>(btq + (size_t)(c0 + cl) * K_RED + r0 + q * 4) = p;
        }
    }
}

// ---------------------------------------------------------------------------
// A-resident streamed GEMM v3 (swapped-operand stores).
// Grid 512 = 64 M-tiles(128 rows) x 8 N-stripes(512 cols). 512 thr = 8 waves;
// wave w owns rows w*16..w*16+15, all 32 cols of each step.
// LDS = 2 x 16KB B dbuf; swizzle both sides: kb ^= (col&7)<<4.
// D = mfma(bf, af): lane l -> m = l&15 (row), n-quad = (l>>4)*4 (+reg).
// ---------------------------------------------------------------------------
__global__ __launch_bounds__(512, 4) void gemm_as3(const char* __restrict__ A,
                                                   const char* __restrict__ Bt,
                                                   float* __restrict__ C) {
    __shared__ char smem[32768];     // 2 x 16KB B double-buffer

    const int tid  = threadIdx.x;
    const int lane = tid & 63;
    const int w    = tid >> 6;       // 0..7 -> m-slice (16 rows)
    const int l15  = lane & 15;
    const int lhi  = lane >> 4;      // 0..3 (k-group for frags, n-quad for D)

    const int b   = blockIdx.x;
    const int n0  = (b & 7) * 512;   // XCD b&7 owns this 256KB B-stripe (L2)
    const int m0  = (b >> 3) * 128;

    auto stageB = [&](int buf, int s) {
        const int sb = buf * 16384;
#pragma unroll
        for (int it = 0; it < 2; ++it) {
            const int o   = (it * 512 + tid) * 16;
            const int col = o >> 9;              // 0..31
            const int kb  = o & 511;
            const char* gb = Bt + (size_t)(n0 + s * 32 + col) * K_RED
                               + (kb ^ ((col & 7) << 4));
            __builtin_amdgcn_global_load_lds(
                (__attribute__((address_space(1))) void*)gb,
                (__attribute__((address_space(3))) void*)(smem + sb + o), 16, 0, 0);
        }
    };

    // Prologue: first B tile staging overlaps direct A-frag loads (xq is
    // LLC-resident, 4MB).
    stageB(0, 0);
    i32x4 af[8];
    {
        const char* ap = A + (size_t)(m0 + w * 16 + l15) * K_RED + lhi * 16;
#pragma unroll
        for (int ks = 0; ks < 8; ++ks)
            af[ks] = *reinterpret_cast<const i32x4*>(ap + ks * 64);
    }
    asm volatile("s_waitcnt vmcnt(0)" ::: "memory");
    __builtin_amdgcn_s_barrier();
    asm volatile("" ::: "memory");

    const int swz = (l15 & 7) << 4;

    for (int s = 0; s < NSTEPS; ++s) {
        const int buf = s & 1;
        if (s < NSTEPS - 1)
            stageB(buf ^ 1, s + 1);
        asm volatile("" ::: "memory");
        const int base = buf * 16384;
        const int b0 = base + l15 * 512;         // col l15
        const int b1 = base + (16 + l15) * 512;  // col 16+l15
        i32x4 acc0 = {}, acc1 = {};
#pragma unroll
        for (int g = 0; g < 2; ++g) {            // bf in 2 batches (VGPR)
            i32x4 bf0[4], bf1[4];
#pragma unroll
            for (int k4 = 0; k4 < 4; ++k4) {
                const int ko = ((g * 4 + k4) * 64 + lhi * 16) ^ swz;
                bf0[k4] = *reinterpret_cast<const i32x4*>(smem + b0 + ko);
                bf1[k4] = *reinterpret_cast<const i32x4*>(smem + b1 + ko);
            }
            __builtin_amdgcn_s_setprio(1);
#pragma unroll
            for (int k4 = 0; k4 < 4; ++k4) {
                const int ks = g * 4 + k4;
                // swapped operands: D[n][m] -> lane: m=l15, n=lhi*4+reg
                acc0 = __builtin_amdgcn_mfma_i32_16x16x64_i8(bf0[k4], af[ks], acc0, 0, 0, 0);
                acc1 = __builtin_amdgcn_mfma_i32_16x16x64_i8(bf1[k4], af[ks], acc1, 0, 0, 0);
            }
            __builtin_amdgcn_s_setprio(0);
        }
        // dwordx4 stores: lane l -> row m0+w*16+l15, cols cb+lhi*4..+3 (acc0)
        // and cb+16+lhi*4..+3 (acc1). One wave covers the full 128B line.
        const size_t row = (size_t)(m0 + w * 16 + l15);
        const int    cb  = n0 + s * 32;
        f32x4 v0, v1;
#pragma unroll
        for (int r = 0; r < 4; ++r) {
            v0[r] = (float)acc0[r] * 0.125f;
            v1[r] = (float)acc1[r] * 0.125f;
        }
        *reinterpret_cast<f32x4*>(&C[row * N_TOT + cb + lhi * 4])      = v0;
        *reinterpret_cast<f32x4*>(&C[row * N_TOT + cb + 16 + lhi * 4]) = v1;
        asm volatile("" ::: "memory");
        if (s < NSTEPS - 1) {
            // outstanding FIFO: [prev 2 stores][2 B-loads][2 stores]
            // vmcnt(2) retires prev stores + loads; this step's stores fly on.
            asm volatile("s_waitcnt vmcnt(2)" ::: "memory");
            __builtin_amdgcn_s_barrier();
            asm volatile("" ::: "memory");
        }
    }
}

// ---------------------------------------------------------------------------
extern "C" void kernel_launch(void* const* d_in, const int* in_sizes, int n_in,
                              void* d_out, int out_size, void* d_ws, size_t ws_size,
                              hipStream_t stream) {
    const float* x   = (const float*)d_in[0];       // [2,4096,4096] f32
    const int*   kin = (const int*)d_in[1];         // [2097152] int32 in {-1,0,1}
    float*       out = (float*)d_out;               // [2,4096,4096] f32

    char* xq  = (char*)d_ws;                                    // 4 MB
    char* btq = (char*)d_ws + (size_t)M_TOT * K_RED;            // 2 MB

    prep<<<dim3(4096 + 512), 256, 0, stream>>>(x, kin, xq, btq);
    gemm_as3<<<dim3(512), 512, 0, stream>>>(xq, btq, out);
}